// Round 9
// baseline (4221.441 us; speedup 1.0000x reference)
//
#include <hip/hip_runtime.h>

// ---------------- problem constants ----------------
#define Bn 32
#define Tn 64
#define Pn 196
#define ENCD 2048
#define DECD 512
#define XDIM 2304

typedef unsigned short u16;
typedef __attribute__((ext_vector_type(8))) short bf16x8;
typedef __attribute__((ext_vector_type(4))) float f32x4;

#define MF(a,b,c) __builtin_amdgcn_mfma_f32_16x16x32_bf16(a,b,c,0,0,0)

static __device__ __forceinline__ u16 f2bf(float f){
  unsigned int u = __float_as_uint(f);
  unsigned int r = u + 0x7FFFu + ((u >> 16) & 1u);
  return (u16)(r >> 16);
}
static __device__ __forceinline__ float bf2f(u16 u){
  return __uint_as_float(((unsigned int)u) << 16);
}

// ---------------- output offsets (floats) ----------------
#define O_PRED   0
#define O_STOP   4096
#define O_SEQOFF 6144
#define O_LEN    10240
#define O_ALPHA  10272
#define O_SORT   411680

// ---------------- ws: f32/int region (f32 indices) ----------------
#define WS_SORT    0        // int[32]
#define WS_LEN     32       // int[32]
#define WS_C       64       // f32 [32][512]
#define WS_PA      16448    // f32 [32][4608] (att2 0..511 | gateRaw 512..2559 | hh 2560..4607)
#define WS_ENCM    215104   // f32 [32][2048]
#define WS_EMB0    280640   // f32 [32][256]
#define WS_BCOMB   288832   // f32 [2048] -> ends 290,880 f32 = 1,163,520 B < 1.6 MB
// ---------------- ws: u16 region (absolute u16 indices from (u16*)d_ws) ----------------
#define US_H0      800000                 // [32][512]
#define US_H1      816384                 // [32][512]
#define US_XA      832768                 // [32][2048]
#define US_EMBBF   898304                 // [32][64][256]
#define US_ATT1T   1422592                // [32][512][208] transposed att1
#define US_ENC     4830464                // [6272][2048] sorted row-major
#define US_WAP     17675520               // [4672][512] Wdec|Wfb|Whh|Wfc(2)|Wstop|pad
#define US_WIHE    20067584               // [2048][256]  jp-interleaved
#define US_WIH2    20591872               // [2048][2048] jp-interleaved
#define US_GEMB    24786176               // [32*64][2048] -> end 28,980,480 u16 = 58.0 MB
#define US_PATCH   20591872               // [2048][3072] ALIAS over WIH2+GEMB head (pre-cvt2)
#define US_WEA     27931904               // [512][2048]  ALIAS in GEMB tail (pre-gemb)

// ============ prep: stable descending sort ============
__global__ void k_prep(const int* __restrict__ caplen, int* __restrict__ ws_sort,
                       int* __restrict__ ws_len, float* __restrict__ out){
  __shared__ int len[32];
  int i = threadIdx.x;
  if (i < 32) len[i] = caplen[i];
  __syncthreads();
  if (i < 32){
    int li = len[i], r = 0;
    for (int j = 0; j < 32; j++){
      int lj = len[j];
      r += (lj > li) || (lj == li && j < i);
    }
    ws_sort[r] = i;
    ws_len[r]  = li;
    out[O_LEN + r]  = (float)li;
    out[O_SORT + r] = (float)i;
  }
}

__global__ void k_seqoff(const float* __restrict__ seqoff, const int* __restrict__ ws_sort,
                         float* __restrict__ out){
  int idx = blockIdx.x*256 + threadIdx.x;
  int b = idx >> 7, r = idx & 127;
  out[O_SEQOFF + idx] = seqoff[ws_sort[b]*128 + r];
}

// ============ enc -> sorted row-major bf16 [6272][2048] ============
__global__ void k_encbf(const float* __restrict__ enc, const int* __restrict__ srt,
                        u16* __restrict__ dst){
  int m = blockIdx.x;
  int b = m / 196, p = m - b*196;
  const float* src = enc + ((size_t)srt[b]*196 + p)*ENCD;
  u16* d = dst + (size_t)m*ENCD;
  int i = threadIdx.x*8;
  float4 v0 = *(const float4*)(src + i);
  float4 v1 = *(const float4*)(src + i + 4);
  bf16x8 s;
  s[0]=(short)f2bf(v0.x); s[1]=(short)f2bf(v0.y); s[2]=(short)f2bf(v0.z); s[3]=(short)f2bf(v0.w);
  s[4]=(short)f2bf(v1.x); s[5]=(short)f2bf(v1.y); s[6]=(short)f2bf(v1.z); s[7]=(short)f2bf(v1.w);
  *(bf16x8*)(d + i) = s;
}

__global__ void k_encmean(const u16* __restrict__ encbf, float* __restrict__ encm){
  int b = blockIdx.x >> 3, dc = blockIdx.x & 7;
  int d = dc*256 + threadIdx.x;
  const u16* ep = encbf + (size_t)(b*196)*ENCD + d;
  float s = 0.f;
  #pragma unroll 4
  for (int p = 0; p < Pn; p++) s += bf2f(ep[(size_t)p*ENCD]);
  encm[b*ENCD + d] = s * (1.f/196.f);
}

// ============ patch extraction -> bf16 ============
__global__ void k_patch(const float* __restrict__ imgs, const int* __restrict__ seq,
                        const int* __restrict__ srt, u16* __restrict__ patches){
  int blk = blockIdx.x; int b = blk>>6, t = blk&63;
  int sb = srt[b];
  int x0 = seq[(sb*64+t)*2 + 0], y0 = seq[(sb*64+t)*2 + 1];
  const float* img = imgs + (size_t)sb*3*512*512;
  u16* dst = patches + (size_t)(b*64+t)*3072;
  for (int idx = threadIdx.x; idx < 3072; idx += 256){
    int c = idx>>10, rem = idx&1023, i = rem>>5, j = rem&31;
    int yy = y0 + i - 24, xx = x0 + j - 24;
    float v = 0.f;
    if ((unsigned)yy < 512u && (unsigned)xx < 512u) v = img[((size_t)c*512 + yy)*512 + xx];
    dst[idx] = f2bf(v);
  }
}

// ============ embed GEMM ============
__global__ __launch_bounds__(256) void k_embedv2(const u16* __restrict__ patches,
    const float* __restrict__ W_pe, const float* __restrict__ b_pe,
    u16* __restrict__ embbf, float* __restrict__ emb0){
  int b = blockIdx.x >> 2, nq = blockIdx.x & 3;
  __shared__ u16 A[64*264];
  int tid = threadIdx.x, wv = tid>>6, lane = tid&63, lr = lane&15, lh = lane>>4;
  int n0 = (nq*4 + wv)*16;
  f32x4 acc[4];
  #pragma unroll
  for (int mt = 0; mt < 4; mt++) acc[mt] = (f32x4){0,0,0,0};
  for (int kc = 0; kc < 12; kc++){
    __syncthreads();
    {
      int row = tid>>2, seg = tid&3;
      const u16* src = patches + (size_t)(b*64 + row)*3072 + kc*256 + seg*64;
      #pragma unroll
      for (int i = 0; i < 8; i++)
        *(bf16x8*)&A[row*264 + seg*64 + i*8] = *(const bf16x8*)(src + i*8);
    }
    __syncthreads();
    #pragma unroll
    for (int ki = 0; ki < 8; ki++){
      const float* wp = W_pe + (size_t)(n0+lr)*3072 + kc*256 + ki*32 + lh*8;
      float4 f0 = *(const float4*)wp, f1 = *(const float4*)(wp + 4);
      bf16x8 bv;
      bv[0]=(short)f2bf(f0.x); bv[1]=(short)f2bf(f0.y); bv[2]=(short)f2bf(f0.z); bv[3]=(short)f2bf(f0.w);
      bv[4]=(short)f2bf(f1.x); bv[5]=(short)f2bf(f1.y); bv[6]=(short)f2bf(f1.z); bv[7]=(short)f2bf(f1.w);
      #pragma unroll
      for (int mt = 0; mt < 4; mt++){
        bf16x8 av = *(const bf16x8*)&A[(mt*16 + lr)*264 + ki*32 + lh*8];
        acc[mt] = MF(av, bv, acc[mt]);
      }
    }
  }
  float bias = b_pe[n0 + lr];
  #pragma unroll
  for (int mt = 0; mt < 4; mt++){
    #pragma unroll
    for (int r = 0; r < 4; r++){
      int ml = mt*16 + lh*4 + r;
      float val = acc[mt][r] + bias;
      embbf[(size_t)(b*64 + ml)*256 + n0 + lr] = f2bf(val);
      if (ml == 0) emb0[b*256 + n0 + lr] = val;
    }
  }
}

// ============ weight converts ============
__global__ void k_cvt2(const float* __restrict__ Wih, const float* __restrict__ Whh,
    const float* __restrict__ Wdec, const float* __restrict__ Wfb,
    const float* __restrict__ Wfc, const float* __restrict__ Wstop,
    const float* __restrict__ Wea, const float* __restrict__ bih, const float* __restrict__ bhh,
    u16* __restrict__ WIH2, u16* __restrict__ WIHE,
    u16* __restrict__ WAP, u16* __restrict__ WEAd, float* __restrict__ bcomb){
  int blk = blockIdx.x, tid = threadIdx.x;
  if (blk < 2048){
    int r = blk, jp = (r & 511)*4 + (r >> 9);
    for (int i = tid; i < 2304; i += 256){
      u16 v = f2bf(Wih[(size_t)r*2304 + i]);
      if (i < 2048) WIH2[(size_t)jp*2048 + i] = v;
      else          WIHE[(size_t)jp*256 + (i - 2048)] = v;
    }
  } else if (blk < 6720){
    int j = blk - 2048;
    const float* src;
    if (j < 512)        src = Wdec + (size_t)j*512;
    else if (j < 2560)  src = Wfb + (size_t)(j-512)*512;
    else if (j < 4608)  src = Whh + (size_t)(j-2560)*512;
    else if (j == 4608) src = Wfc;
    else if (j == 4609) src = Wfc + 512;
    else if (j == 4610) src = Wstop;
    else src = 0;
    for (int i = tid; i < 512; i += 256)
      WAP[(size_t)j*512 + i] = src ? f2bf(src[i]) : (u16)0;
  } else if (blk < 7232){
    int r = blk - 6720;
    for (int i = tid; i < 2048; i += 256)
      WEAd[(size_t)r*2048 + i] = f2bf(Wea[(size_t)r*2048 + i]);
  } else {
    int jp = (blk - 7232)*256 + tid;
    int r = (jp & 3)*512 + (jp >> 2);
    bcomb[jp] = bih[r] + bhh[r];
  }
}

// ============ G_emb = emb @ WIHE^T ============
__global__ __launch_bounds__(256) void k_gemb(const u16* __restrict__ embbf,
    const u16* __restrict__ WIHE, u16* __restrict__ gemb){
  int m0 = (blockIdx.x >> 3)*64, n0 = (blockIdx.x & 7)*256;
  __shared__ u16 A[64*264];
  int tid = threadIdx.x, wv = tid>>6, lane = tid&63, lr = lane&15, lh = lane>>4;
  {
    int row = tid>>2, seg = tid&3;
    const u16* src = embbf + (size_t)(m0 + row)*256 + seg*64;
    #pragma unroll
    for (int i = 0; i < 8; i++)
      *(bf16x8*)&A[row*264 + seg*64 + i*8] = *(const bf16x8*)(src + i*8);
  }
  __syncthreads();
  f32x4 acc[4][4];
  #pragma unroll
  for (int mt = 0; mt < 4; mt++)
    #pragma unroll
    for (int nt = 0; nt < 4; nt++) acc[mt][nt] = (f32x4){0,0,0,0};
  #pragma unroll
  for (int ki = 0; ki < 8; ki++){
    bf16x8 av[4];
    #pragma unroll
    for (int mt = 0; mt < 4; mt++)
      av[mt] = *(const bf16x8*)&A[(mt*16 + lr)*264 + ki*32 + lh*8];
    #pragma unroll
    for (int nt = 0; nt < 4; nt++){
      bf16x8 bv = *(const bf16x8*)&WIHE[(size_t)(n0 + wv*64 + nt*16 + lr)*256 + ki*32 + lh*8];
      #pragma unroll
      for (int mt = 0; mt < 4; mt++) acc[mt][nt] = MF(av[mt], bv, acc[mt][nt]);
    }
  }
  #pragma unroll
  for (int nt = 0; nt < 4; nt++){
    int n = n0 + wv*64 + nt*16 + lr;
    #pragma unroll
    for (int mt = 0; mt < 4; mt++)
      #pragma unroll
      for (int r = 0; r < 4; r++)
        gemb[(size_t)(m0 + mt*16 + lh*4 + r)*2048 + n] = f2bf(acc[mt][nt][r]);
  }
}

// ============ att1 (MFMA, fp32 source) -> TRANSPOSED att1T[b][512][208] ============
__global__ __launch_bounds__(256) void k_att1v2(const float* __restrict__ enc,
    const int* __restrict__ srt, const u16* __restrict__ Wea,
    const float* __restrict__ bea, u16* __restrict__ att1T){
  int m0 = blockIdx.x*64;
  __shared__ u16 A[64*136];
  __shared__ size_t rowbase[64];
  int tid = threadIdx.x, wv = tid>>6, lane = tid&63, lr = lane&15, lh = lane>>4;
  if (tid < 64){
    int m = m0 + tid, bb = m/196, p = m - bb*196;
    rowbase[tid] = ((size_t)srt[bb]*196 + p)*2048;
  }
  f32x4 acc[4][8];
  #pragma unroll
  for (int mt = 0; mt < 4; mt++)
    #pragma unroll
    for (int nt = 0; nt < 8; nt++) acc[mt][nt] = (f32x4){0,0,0,0};
  for (int kc = 0; kc < 16; kc++){
    __syncthreads();
    {
      int row = tid>>2, seg = tid&3;
      const float* src = enc + rowbase[row] + kc*128 + seg*32;
      #pragma unroll
      for (int i = 0; i < 8; i++){
        float4 v = *(const float4*)(src + i*4);
        u16* dp = &A[row*136 + seg*32 + i*4];
        dp[0]=f2bf(v.x); dp[1]=f2bf(v.y); dp[2]=f2bf(v.z); dp[3]=f2bf(v.w);
      }
    }
    __syncthreads();
    #pragma unroll
    for (int ki = 0; ki < 4; ki++){
      bf16x8 av[4];
      #pragma unroll
      for (int mt = 0; mt < 4; mt++)
        av[mt] = *(const bf16x8*)&A[(mt*16 + lr)*136 + ki*32 + lh*8];
      #pragma unroll
      for (int nt = 0; nt < 8; nt++){
        const u16* wp = Wea + (size_t)(wv*128 + nt*16 + lr)*2048 + kc*128 + ki*32 + lh*8;
        bf16x8 bv = *(const bf16x8*)wp;
        #pragma unroll
        for (int mt = 0; mt < 4; mt++) acc[mt][nt] = MF(av[mt], bv, acc[mt][nt]);
      }
    }
  }
  #pragma unroll
  for (int nt = 0; nt < 8; nt++){
    int n = wv*128 + nt*16 + lr;
    float bias = bea[n];
    #pragma unroll
    for (int mt = 0; mt < 4; mt++){
      #pragma unroll
      for (int r = 0; r < 4; r++){
        int m = m0 + mt*16 + lh*4 + r;
        int bb = m / 196, pp = m - bb*196;
        att1T[((size_t)bb*512 + n)*208 + pp] = f2bf(acc[mt][nt][r] + bias);
      }
    }
  }
}

// ============ h,c init ============
__global__ __launch_bounds__(256) void k_init(const float* __restrict__ encm, const float* __restrict__ emb0,
    const float* __restrict__ Wh, const float* __restrict__ bh,
    const float* __restrict__ Wc, const float* __restrict__ bc,
    u16* __restrict__ h_bf, float* __restrict__ c){
  int mat = blockIdx.x >> 4, jb = blockIdx.x & 15;
  const float* W    = mat ? Wc : Wh;
  const float* bias = mat ? bc : bh;
  int j0 = jb*32;
  __shared__ float XT[256*36];
  int bq = threadIdx.x & 7, jq = threadIdx.x >> 3;
  float acc[4] = {0.f,0.f,0.f,0.f};
  for (int ch = 0; ch < 9; ch++){
    int k0 = ch*256;
    __syncthreads();
    {
      int m = threadIdx.x >> 3, kq8 = threadIdx.x & 7;
      #pragma unroll
      for (int i = 0; i < 8; i++){
        int kq = kq8 + i*8;
        int k = k0 + kq*4;
        float4 v;
        if (k < 2048) v = *(const float4*)&encm[m*ENCD + k];
        else          v = *(const float4*)&emb0[m*256 + (k - 2048)];
        XT[(4*kq+0)*36+m]=v.x; XT[(4*kq+1)*36+m]=v.y; XT[(4*kq+2)*36+m]=v.z; XT[(4*kq+3)*36+m]=v.w;
      }
    }
    __syncthreads();
    int j = j0 + jq;
    const float* wr = W + (size_t)j*XDIM + k0;
    #pragma unroll 2
    for (int k4 = 0; k4 < 64; k4++){
      float4 wv = *(const float4*)(wr + k4*4);
      float4 x0 = *(float4*)&XT[(k4*4+0)*36 + bq*4];
      float4 x1 = *(float4*)&XT[(k4*4+1)*36 + bq*4];
      float4 x2 = *(float4*)&XT[(k4*4+2)*36 + bq*4];
      float4 x3 = *(float4*)&XT[(k4*4+3)*36 + bq*4];
      acc[0] += x0.x*wv.x + x1.x*wv.y + x2.x*wv.z + x3.x*wv.w;
      acc[1] += x0.y*wv.x + x1.y*wv.y + x2.y*wv.z + x3.y*wv.w;
      acc[2] += x0.z*wv.x + x1.z*wv.y + x2.z*wv.z + x3.z*wv.w;
      acc[3] += x0.w*wv.x + x1.w*wv.y + x2.w*wv.z + x3.w*wv.w;
    }
  }
  #pragma unroll
  for (int bb = 0; bb < 4; bb++){
    float v = acc[bb] + bias[j0 + jq];
    int row = bq*4 + bb;
    if (mat == 0) h_bf[row*DECD + j0 + jq] = f2bf(v);
    else          c[row*DECD + j0 + jq] = v;
  }
}

// ============ kA: pA = h @ [Wdec|Wfb|Whh]^T ; preds/stop(t-1) ============
__global__ __launch_bounds__(256) void kA(const u16* __restrict__ h, const u16* __restrict__ WAP,
    float* __restrict__ pA, const float* __restrict__ bfc, const float* __restrict__ bstop,
    const int* __restrict__ len, float* __restrict__ out, int t){
  __shared__ u16 HL[32*520];
  int tid = threadIdx.x, wv = tid>>6, lane = tid&63, lr = lane&15, lh = lane>>4;
  for (int i = tid; i < 4096; i += 256){
    unsigned long long v = ((const unsigned long long*)h)[i];
    int row = i >> 7, col = (i & 127)*4;
    *(unsigned long long*)&HL[row*520 + col] = v;
  }
  __syncthreads();
  int j0 = blockIdx.x*64 + wv*16;
  f32x4 acc0 = {0,0,0,0}, acc1 = {0,0,0,0};
  #pragma unroll 4
  for (int ki = 0; ki < 16; ++ki){
    bf16x8 bv = *(const bf16x8*)&WAP[(size_t)(j0+lr)*512 + ki*32 + lh*8];
    bf16x8 a0 = *(const bf16x8*)&HL[lr*520 + ki*32 + lh*8];
    bf16x8 a1 = *(const bf16x8*)&HL[(16+lr)*520 + ki*32 + lh*8];
    acc0 = MF(a0, bv, acc0);
    acc1 = MF(a1, bv, acc1);
  }
  int j = j0 + lr;
  if (j < 4608){
    #pragma unroll
    for (int r = 0; r < 4; ++r){
      pA[(size_t)(lh*4+r)*4608 + j]    = acc0[r];
      pA[(size_t)(lh*4+r+16)*4608 + j] = acc1[r];
    }
  } else if (j < 4611 && t > 0){
    int jj = j - 4608, tm1 = t - 1;
    #pragma unroll
    for (int r = 0; r < 4; ++r){
      #pragma unroll
      for (int hb = 0; hb < 2; ++hb){
        int b0 = lh*4 + r + hb*16;
        float val = hb ? acc1[r] : acc0[r];
        bool mk = tm1 < len[b0];
        if (jj < 2) out[O_PRED + ((size_t)b0*64 + tm1)*2 + jj] = mk ? val + bfc[jj] : 0.f;
        else        out[O_STOP + (size_t)b0*64 + tm1] =
                      mk ? 1.f/(1.f + expf(-(val + bstop[0]))) : 0.f;
      }
    }
  }
}

// ============ kB: scores (LDS partials) + softmax + awe + gate -> xa ; alphas ============
// grid 64 = 32 b * 2 halves (half owns 1024 d); scores/softmax computed in both halves.
__global__ __launch_bounds__(512) void kB(const float* __restrict__ pA,
    const u16* __restrict__ att1T, const u16* __restrict__ encbf,
    const float* __restrict__ bdec, const float* __restrict__ wfull,
    const float* __restrict__ bfull, const float* __restrict__ bfb,
    u16* __restrict__ xa, const int* __restrict__ len, float* __restrict__ out, int t){
  int b = blockIdx.x >> 1, half = blockIdx.x & 1;
  int tid = threadIdx.x, wv = tid>>6, lane = tid&63;
  if (t >= len[b]){
    if (half == 0 && tid < 196) out[O_ALPHA + ((size_t)b*64 + t)*196 + tid] = 0.f;
    return;
  }
  __shared__ float a2[512], wf[512];
  __shared__ float scp[8][200];
  __shared__ float ev[200], redf[8], bcx[2];
  a2[tid] = pA[(size_t)b*4608 + tid] + bdec[tid];
  wf[tid] = wfull[tid];
  __syncthreads();
  // score partials: 2048 tasks = 8 a-chunks x 256 p-slots (p<196 active), coalesced along p
  #pragma unroll
  for (int pass = 0; pass < 4; ++pass){
    int task = pass*512 + tid;
    int ac = task >> 8, p = task & 255;
    if (p < 196){
      const u16* col = att1T + ((size_t)b*512 + ac*64)*208 + p;
      const float* ap = a2 + ac*64;
      const float* wp = wf + ac*64;
      float acc = 0.f;
      #pragma unroll 8
      for (int a = 0; a < 64; ++a)
        acc += fmaxf(bf2f(col[(size_t)a*208]) + ap[a], 0.f) * wp[a];
      scp[ac][p] = acc;
    }
  }
  __syncthreads();
  float s = -1e30f;
  if (tid < 196){
    s = bfull[0];
    #pragma unroll
    for (int q = 0; q < 8; ++q) s += scp[q][tid];
  }
  float m = s;
  #pragma unroll
  for (int o = 32; o; o >>= 1) m = fmaxf(m, __shfl_down(m, o));
  if (lane == 0) redf[wv] = m;
  __syncthreads();
  if (tid == 0){
    float mm = redf[0];
    #pragma unroll
    for (int i = 1; i < 8; ++i) mm = fmaxf(mm, redf[i]);
    bcx[0] = mm;
  }
  __syncthreads();
  float e = (tid < 196) ? expf(s - bcx[0]) : 0.f;
  if (tid < 200) ev[tid] = (tid < 196) ? e : 0.f;
  float sm = e;
  #pragma unroll
  for (int o = 32; o; o >>= 1) sm += __shfl_down(sm, o);
  __syncthreads();
  if (lane == 0) redf[wv] = sm;
  __syncthreads();
  if (tid == 0){
    float ss = 0.f;
    #pragma unroll
    for (int i = 0; i < 8; ++i) ss += redf[i];
    bcx[1] = ss;
  }
  __syncthreads();
  float ssum = bcx[1];
  #pragma unroll
  for (int it = 0; it < 2; ++it){
    int d = half*1024 + it*512 + tid;
    const u16* ep = encbf + (size_t)(b*196)*ENCD + d;
    float q0=0.f, q1=0.f, q2=0.f, q3=0.f;
    #pragma unroll 4
    for (int p = 0; p < 196; p += 4){
      q0 += ev[p+0]*bf2f(ep[(size_t)(p+0)*ENCD]);
      q1 += ev[p+1]*bf2f(ep[(size_t)(p+1)*ENCD]);
      q2 += ev[p+2]*bf2f(ep[(size_t)(p+2)*ENCD]);
      q3 += ev[p+3]*bf2f(ep[(size_t)(p+3)*ENCD]);
    }
    float awe = ((q0+q1)+(q2+q3)) / ssum;
    float gp = pA[(size_t)b*4608 + 512 + d] + bfb[d];
    float gate = 1.f/(1.f + expf(-gp));
    xa[(size_t)b*2048 + d] = f2bf(gate * awe);
  }
  if (half == 0 && tid < 196) out[O_ALPHA + ((size_t)b*64 + t)*196 + tid] = ev[tid]/ssum;
}

// ============ kC: gates GEMM (8-wave K-split) + LSTM fused ============
__global__ __launch_bounds__(512) void kC(const u16* __restrict__ xa,
    const u16* __restrict__ hc, u16* __restrict__ hn, float* __restrict__ c,
    const u16* __restrict__ WIH2, const float* __restrict__ pA,
    const float* __restrict__ bcomb, const u16* __restrict__ gemb,
    const int* __restrict__ len, int t){
  int tid = threadIdx.x, wv = tid>>6, lane = tid&63, lr = lane&15, lh = lane>>4;
  int jp0 = blockIdx.x*16;
  __shared__ float red[8*512];
  f32x4 acc0 = {0,0,0,0}, acc1 = {0,0,0,0};
  #pragma unroll
  for (int ks = 0; ks < 8; ++ks){
    int k = wv*256 + ks*32;
    bf16x8 a0 = *(const bf16x8*)&xa[(size_t)lr*2048 + k + lh*8];
    bf16x8 a1 = *(const bf16x8*)&xa[(size_t)(16+lr)*2048 + k + lh*8];
    bf16x8 bv = *(const bf16x8*)&WIH2[(size_t)(jp0+lr)*2048 + k + lh*8];
    acc0 = MF(a0, bv, acc0);
    acc1 = MF(a1, bv, acc1);
  }
  #pragma unroll
  for (int r = 0; r < 4; ++r){
    red[wv*512 + ((lh*4+r) << 4) + lr]    = acc0[r];
    red[wv*512 + ((16+lh*4+r) << 4) + lr] = acc1[r];
  }
  __syncthreads();
  {
    int b = tid >> 4, jl = tid & 15, e = jl & 3;
    int jp = jp0 + jl, u = jp >> 2;
    float g = 0.f;
    #pragma unroll
    for (int w = 0; w < 8; ++w) g += red[w*512 + tid];
    g += bcomb[jp] + bf2f(gemb[((size_t)b*64 + t)*2048 + jp])
       + pA[(size_t)b*4608 + 2560 + e*512 + u];
    float sv = (e == 2) ? tanhf(g) : 1.f/(1.f + expf(-g));
    float vb = __shfl_xor(sv, 1), vc = __shfl_xor(sv, 2), vd = __shfl_xor(vb, 2);
    float i_s = (e==0)?sv:(e==1)?vb:(e==2)?vc:vd;
    float f_s = (e==1)?sv:(e==0)?vb:(e==3)?vc:vd;
    float g_t = (e==2)?sv:(e==3)?vb:(e==0)?vc:vd;
    float o_s = (e==3)?sv:(e==2)?vb:(e==1)?vc:vd;
    float cold = c[(size_t)b*512 + u];
    float hold = bf2f(hc[(size_t)b*512 + u]);
    bool mk = t < len[b];
    float cn = mk ? (f_s*cold + i_s*g_t) : cold;
    float hv = mk ? (o_s * tanhf(cn)) : hold;
    if (e == 0){
      c[(size_t)b*512 + u] = cn;
      hn[(size_t)b*512 + u] = f2bf(hv);
    }
  }
}

// ================= host launcher =================
extern "C" void kernel_launch(void* const* d_in, const int* in_sizes, int n_in,
                              void* d_out, int out_size, void* d_ws, size_t ws_size,
                              hipStream_t stream){
  (void)in_sizes; (void)n_in; (void)out_size; (void)ws_size;
  const float* enc_out   = (const float*)d_in[0];
  const float* imgs      = (const float*)d_in[1];
  const int*   seq       = (const int*)d_in[2];
  const float* seqoff    = (const float*)d_in[3];
  const int*   caplen    = (const int*)d_in[4];
  const float* W_pe      = (const float*)d_in[5];
  const float* b_pe      = (const float*)d_in[6];
  const float* W_enc_att = (const float*)d_in[7];
  const float* b_enc_att = (const float*)d_in[8];
  const float* W_dec_att = (const float*)d_in[9];
  const float* b_dec_att = (const float*)d_in[10];
  const float* w_full    = (const float*)d_in[11];
  const float* b_full    = (const float*)d_in[12];
  const float* W_init_h  = (const float*)d_in[13];
  const float* b_init_h  = (const float*)d_in[14];
  const float* W_init_c  = (const float*)d_in[15];
  const float* b_init_c  = (const float*)d_in[16];
  const float* W_fb      = (const float*)d_in[17];
  const float* b_fb      = (const float*)d_in[18];
  const float* W_ih      = (const float*)d_in[19];
  const float* b_ih      = (const float*)d_in[20];
  const float* W_hh      = (const float*)d_in[21];
  const float* b_hh      = (const float*)d_in[22];
  const float* W_fc      = (const float*)d_in[23];
  const float* b_fc      = (const float*)d_in[24];
  const float* W_stop    = (const float*)d_in[25];
  const float* b_stop    = (const float*)d_in[26];

  float* out = (float*)d_out;
  float* ws  = (float*)d_ws;
  int*   wsi = (int*)d_ws;
  u16*   us  = (u16*)d_ws;

  u16* H[2] = { us + US_H0, us + US_H1 };

  k_prep<<<1, 64, 0, stream>>>(caplen, wsi + WS_SORT, wsi + WS_LEN, out);
  k_seqoff<<<16, 256, 0, stream>>>(seqoff, wsi + WS_SORT, out);
  k_encbf<<<6272, 256, 0, stream>>>(enc_out, wsi + WS_SORT, us + US_ENC);
  k_encmean<<<256, 256, 0, stream>>>(us + US_ENC, ws + WS_ENCM);
  k_patch<<<2048, 256, 0, stream>>>(imgs, seq, wsi + WS_SORT, us + US_PATCH);
  k_embedv2<<<128, 256, 0, stream>>>(us + US_PATCH, W_pe, b_pe, us + US_EMBBF, ws + WS_EMB0);
  k_cvt2<<<7240, 256, 0, stream>>>(W_ih, W_hh, W_dec_att, W_fb, W_fc, W_stop, W_enc_att,
                                   b_ih, b_hh,
                                   us + US_WIH2, us + US_WIHE, us + US_WAP,
                                   us + US_WEA, ws + WS_BCOMB);
  k_att1v2<<<98, 256, 0, stream>>>(enc_out, wsi + WS_SORT, us + US_WEA, b_enc_att, us + US_ATT1T);
  k_gemb<<<256, 256, 0, stream>>>(us + US_EMBBF, us + US_WIHE, us + US_GEMB);
  k_init<<<32, 256, 0, stream>>>(ws + WS_ENCM, ws + WS_EMB0, W_init_h, b_init_h,
                                 W_init_c, b_init_c, H[0], ws + WS_C);

  for (int t = 0; t < Tn; ++t){
    kA<<<73, 256, 0, stream>>>(H[t & 1], us + US_WAP, ws + WS_PA, b_fc, b_stop,
                               wsi + WS_LEN, out, t);
    kB<<<64, 512, 0, stream>>>(ws + WS_PA, us + US_ATT1T, us + US_ENC,
                               b_dec_att, w_full, b_full, b_fb,
                               us + US_XA, wsi + WS_LEN, out, t);
    kC<<<128, 512, 0, stream>>>(us + US_XA, H[t & 1], H[(t + 1) & 1], ws + WS_C,
                                us + US_WIH2, ws + WS_PA, ws + WS_BCOMB, us + US_GEMB,
                                wsi + WS_LEN, t);
  }
  kA<<<73, 256, 0, stream>>>(H[0], us + US_WAP, ws + WS_PA, b_fc, b_stop,
                             wsi + WS_LEN, out, 64);
}

// Round 10
// 2371.280 us; speedup vs baseline: 1.7802x; 1.7802x over previous
//
#include <hip/hip_runtime.h>

// ---------------- problem constants ----------------
#define Bn 32
#define Tn 64
#define Pn 196
#define ENCD 2048
#define DECD 512
#define XDIM 2304

typedef unsigned short u16;
typedef __attribute__((ext_vector_type(8))) short bf16x8;
typedef __attribute__((ext_vector_type(4))) float f32x4;

#define MF(a,b,c) __builtin_amdgcn_mfma_f32_16x16x32_bf16(a,b,c,0,0,0)

static __device__ __forceinline__ u16 f2bf(float f){
  unsigned int u = __float_as_uint(f);
  unsigned int r = u + 0x7FFFu + ((u >> 16) & 1u);
  return (u16)(r >> 16);
}
static __device__ __forceinline__ float bf2f(u16 u){
  return __uint_as_float(((unsigned int)u) << 16);
}

// ---------------- output offsets (floats) ----------------
#define O_PRED   0
#define O_STOP   4096
#define O_SEQOFF 6144
#define O_LEN    10240
#define O_ALPHA  10272
#define O_SORT   411680

// ---------------- ws: f32/int region (f32 indices) ----------------
#define WS_SORT    0        // int[32]
#define WS_LEN     32       // int[32]
#define WS_C       64       // f32 [32][512]
#define WS_PA      16448    // f32 [32][4608] (att2 0..511 | gateRaw 512..2559 | hh 2560..4607)
#define WS_SCP     163904   // f32 [32][8][200] score partials
#define WS_ENCM    215104   // f32 [32][2048]
#define WS_EMB0    280640   // f32 [32][256]
#define WS_BCOMB   288832   // f32 [2048] -> ends 290,880 f32 = 1,163,520 B < 1.6 MB
// ---------------- ws: u16 region (absolute u16 indices from (u16*)d_ws) ----------------
#define US_H0      800000                 // [32][512]
#define US_H1      816384                 // [32][512]
#define US_XA      832768                 // [32][2048]
#define US_EMBBF   898304                 // [32][64][256]
#define US_ATT1T   1422592                // [32][512][208] transposed att1
#define US_ENC     4830464                // [6272][2048] sorted row-major
#define US_WAP     17675520               // [4672][512] Wdec|Wfb|Whh|Wfc(2)|Wstop|pad
#define US_WIHE    20067584               // [2048][256]  jp-interleaved
#define US_WIH2    20591872               // [2048][2048] jp-interleaved
#define US_GEMB    24786176               // [32*64][2048] -> end 28,980,480 u16 = 58.0 MB
#define US_PATCH   20591872               // [2048][3072] ALIAS over WIH2+GEMB head (pre-cvt2)
#define US_WEA     27931904               // [512][2048]  ALIAS in GEMB tail (pre-gemb)

// ============ prep: stable descending sort ============
__global__ void k_prep(const int* __restrict__ caplen, int* __restrict__ ws_sort,
                       int* __restrict__ ws_len, float* __restrict__ out){
  __shared__ int len[32];
  int i = threadIdx.x;
  if (i < 32) len[i] = caplen[i];
  __syncthreads();
  if (i < 32){
    int li = len[i], r = 0;
    for (int j = 0; j < 32; j++){
      int lj = len[j];
      r += (lj > li) || (lj == li && j < i);
    }
    ws_sort[r] = i;
    ws_len[r]  = li;
    out[O_LEN + r]  = (float)li;
    out[O_SORT + r] = (float)i;
  }
}

__global__ void k_seqoff(const float* __restrict__ seqoff, const int* __restrict__ ws_sort,
                         float* __restrict__ out){
  int idx = blockIdx.x*256 + threadIdx.x;
  int b = idx >> 7, r = idx & 127;
  out[O_SEQOFF + idx] = seqoff[ws_sort[b]*128 + r];
}

// ============ enc -> sorted row-major bf16 [6272][2048] ============
__global__ void k_encbf(const float* __restrict__ enc, const int* __restrict__ srt,
                        u16* __restrict__ dst){
  int m = blockIdx.x;
  int b = m / 196, p = m - b*196;
  const float* src = enc + ((size_t)srt[b]*196 + p)*ENCD;
  u16* d = dst + (size_t)m*ENCD;
  int i = threadIdx.x*8;
  float4 v0 = *(const float4*)(src + i);
  float4 v1 = *(const float4*)(src + i + 4);
  bf16x8 s;
  s[0]=(short)f2bf(v0.x); s[1]=(short)f2bf(v0.y); s[2]=(short)f2bf(v0.z); s[3]=(short)f2bf(v0.w);
  s[4]=(short)f2bf(v1.x); s[5]=(short)f2bf(v1.y); s[6]=(short)f2bf(v1.z); s[7]=(short)f2bf(v1.w);
  *(bf16x8*)(d + i) = s;
}

__global__ void k_encmean(const u16* __restrict__ encbf, float* __restrict__ encm){
  int b = blockIdx.x >> 3, dc = blockIdx.x & 7;
  int d = dc*256 + threadIdx.x;
  const u16* ep = encbf + (size_t)(b*196)*ENCD + d;
  float s = 0.f;
  #pragma unroll 4
  for (int p = 0; p < Pn; p++) s += bf2f(ep[(size_t)p*ENCD]);
  encm[b*ENCD + d] = s * (1.f/196.f);
}

// ============ patch extraction -> bf16 ============
__global__ void k_patch(const float* __restrict__ imgs, const int* __restrict__ seq,
                        const int* __restrict__ srt, u16* __restrict__ patches){
  int blk = blockIdx.x; int b = blk>>6, t = blk&63;
  int sb = srt[b];
  int x0 = seq[(sb*64+t)*2 + 0], y0 = seq[(sb*64+t)*2 + 1];
  const float* img = imgs + (size_t)sb*3*512*512;
  u16* dst = patches + (size_t)(b*64+t)*3072;
  for (int idx = threadIdx.x; idx < 3072; idx += 256){
    int c = idx>>10, rem = idx&1023, i = rem>>5, j = rem&31;
    int yy = y0 + i - 24, xx = x0 + j - 24;
    float v = 0.f;
    if ((unsigned)yy < 512u && (unsigned)xx < 512u) v = img[((size_t)c*512 + yy)*512 + xx];
    dst[idx] = f2bf(v);
  }
}

// ============ embed GEMM ============
__global__ __launch_bounds__(256) void k_embedv2(const u16* __restrict__ patches,
    const float* __restrict__ W_pe, const float* __restrict__ b_pe,
    u16* __restrict__ embbf, float* __restrict__ emb0){
  int b = blockIdx.x >> 2, nq = blockIdx.x & 3;
  __shared__ u16 A[64*264];
  int tid = threadIdx.x, wv = tid>>6, lane = tid&63, lr = lane&15, lh = lane>>4;
  int n0 = (nq*4 + wv)*16;
  f32x4 acc[4];
  #pragma unroll
  for (int mt = 0; mt < 4; mt++) acc[mt] = (f32x4){0,0,0,0};
  for (int kc = 0; kc < 12; kc++){
    __syncthreads();
    {
      int row = tid>>2, seg = tid&3;
      const u16* src = patches + (size_t)(b*64 + row)*3072 + kc*256 + seg*64;
      #pragma unroll
      for (int i = 0; i < 8; i++)
        *(bf16x8*)&A[row*264 + seg*64 + i*8] = *(const bf16x8*)(src + i*8);
    }
    __syncthreads();
    #pragma unroll
    for (int ki = 0; ki < 8; ki++){
      const float* wp = W_pe + (size_t)(n0+lr)*3072 + kc*256 + ki*32 + lh*8;
      float4 f0 = *(const float4*)wp, f1 = *(const float4*)(wp + 4);
      bf16x8 bv;
      bv[0]=(short)f2bf(f0.x); bv[1]=(short)f2bf(f0.y); bv[2]=(short)f2bf(f0.z); bv[3]=(short)f2bf(f0.w);
      bv[4]=(short)f2bf(f1.x); bv[5]=(short)f2bf(f1.y); bv[6]=(short)f2bf(f1.z); bv[7]=(short)f2bf(f1.w);
      #pragma unroll
      for (int mt = 0; mt < 4; mt++){
        bf16x8 av = *(const bf16x8*)&A[(mt*16 + lr)*264 + ki*32 + lh*8];
        acc[mt] = MF(av, bv, acc[mt]);
      }
    }
  }
  float bias = b_pe[n0 + lr];
  #pragma unroll
  for (int mt = 0; mt < 4; mt++){
    #pragma unroll
    for (int r = 0; r < 4; r++){
      int ml = mt*16 + lh*4 + r;
      float val = acc[mt][r] + bias;
      embbf[(size_t)(b*64 + ml)*256 + n0 + lr] = f2bf(val);
      if (ml == 0) emb0[b*256 + n0 + lr] = val;
    }
  }
}

// ============ weight converts ============
__global__ void k_cvt2(const float* __restrict__ Wih, const float* __restrict__ Whh,
    const float* __restrict__ Wdec, const float* __restrict__ Wfb,
    const float* __restrict__ Wfc, const float* __restrict__ Wstop,
    const float* __restrict__ Wea, const float* __restrict__ bih, const float* __restrict__ bhh,
    u16* __restrict__ WIH2, u16* __restrict__ WIHE,
    u16* __restrict__ WAP, u16* __restrict__ WEAd, float* __restrict__ bcomb){
  int blk = blockIdx.x, tid = threadIdx.x;
  if (blk < 2048){
    int r = blk, jp = (r & 511)*4 + (r >> 9);
    for (int i = tid; i < 2304; i += 256){
      u16 v = f2bf(Wih[(size_t)r*2304 + i]);
      if (i < 2048) WIH2[(size_t)jp*2048 + i] = v;
      else          WIHE[(size_t)jp*256 + (i - 2048)] = v;
    }
  } else if (blk < 6720){
    int j = blk - 2048;
    const float* src;
    if (j < 512)        src = Wdec + (size_t)j*512;
    else if (j < 2560)  src = Wfb + (size_t)(j-512)*512;
    else if (j < 4608)  src = Whh + (size_t)(j-2560)*512;
    else if (j == 4608) src = Wfc;
    else if (j == 4609) src = Wfc + 512;
    else if (j == 4610) src = Wstop;
    else src = 0;
    for (int i = tid; i < 512; i += 256)
      WAP[(size_t)j*512 + i] = src ? f2bf(src[i]) : (u16)0;
  } else if (blk < 7232){
    int r = blk - 6720;
    for (int i = tid; i < 2048; i += 256)
      WEAd[(size_t)r*2048 + i] = f2bf(Wea[(size_t)r*2048 + i]);
  } else {
    int jp = (blk - 7232)*256 + tid;
    int r = (jp & 3)*512 + (jp >> 2);
    bcomb[jp] = bih[r] + bhh[r];
  }
}

// ============ G_emb = emb @ WIHE^T ============
__global__ __launch_bounds__(256) void k_gemb(const u16* __restrict__ embbf,
    const u16* __restrict__ WIHE, u16* __restrict__ gemb){
  int m0 = (blockIdx.x >> 3)*64, n0 = (blockIdx.x & 7)*256;
  __shared__ u16 A[64*264];
  int tid = threadIdx.x, wv = tid>>6, lane = tid&63, lr = lane&15, lh = lane>>4;
  {
    int row = tid>>2, seg = tid&3;
    const u16* src = embbf + (size_t)(m0 + row)*256 + seg*64;
    #pragma unroll
    for (int i = 0; i < 8; i++)
      *(bf16x8*)&A[row*264 + seg*64 + i*8] = *(const bf16x8*)(src + i*8);
  }
  __syncthreads();
  f32x4 acc[4][4];
  #pragma unroll
  for (int mt = 0; mt < 4; mt++)
    #pragma unroll
    for (int nt = 0; nt < 4; nt++) acc[mt][nt] = (f32x4){0,0,0,0};
  #pragma unroll
  for (int ki = 0; ki < 8; ki++){
    bf16x8 av[4];
    #pragma unroll
    for (int mt = 0; mt < 4; mt++)
      av[mt] = *(const bf16x8*)&A[(mt*16 + lr)*264 + ki*32 + lh*8];
    #pragma unroll
    for (int nt = 0; nt < 4; nt++){
      bf16x8 bv = *(const bf16x8*)&WIHE[(size_t)(n0 + wv*64 + nt*16 + lr)*256 + ki*32 + lh*8];
      #pragma unroll
      for (int mt = 0; mt < 4; mt++) acc[mt][nt] = MF(av[mt], bv, acc[mt][nt]);
    }
  }
  #pragma unroll
  for (int nt = 0; nt < 4; nt++){
    int n = n0 + wv*64 + nt*16 + lr;
    #pragma unroll
    for (int mt = 0; mt < 4; mt++)
      #pragma unroll
      for (int r = 0; r < 4; r++)
        gemb[(size_t)(m0 + mt*16 + lh*4 + r)*2048 + n] = f2bf(acc[mt][nt][r]);
  }
}

// ============ att1 v4 (bf16 source, N-split 4) -> TRANSPOSED att1T[b][512][208] ============
// grid 392 = 98 mb(64 m) x 4 nb(128 n); 4 waves each own 32 n
__global__ __launch_bounds__(256) void k_att1v4(const u16* __restrict__ encbf,
    const u16* __restrict__ Wea, const float* __restrict__ bea, u16* __restrict__ att1T){
  int mb = blockIdx.x >> 2, nb = blockIdx.x & 3;
  int m0 = mb*64;
  __shared__ u16 A[64*136];
  int tid = threadIdx.x, wv = tid>>6, lane = tid&63, lr = lane&15, lh = lane>>4;
  f32x4 acc[4][2];
  #pragma unroll
  for (int mt = 0; mt < 4; mt++){ acc[mt][0] = (f32x4){0,0,0,0}; acc[mt][1] = (f32x4){0,0,0,0}; }
  for (int kc = 0; kc < 16; kc++){
    __syncthreads();
    {
      int row = tid>>2, seg = tid&3;
      const u16* src = encbf + (size_t)(m0 + row)*2048 + kc*128 + seg*32;
      #pragma unroll
      for (int i = 0; i < 4; i++)
        *(bf16x8*)&A[row*136 + seg*32 + i*8] = *(const bf16x8*)(src + i*8);
    }
    __syncthreads();
    #pragma unroll
    for (int ki = 0; ki < 4; ki++){
      bf16x8 av[4];
      #pragma unroll
      for (int mt = 0; mt < 4; mt++)
        av[mt] = *(const bf16x8*)&A[(mt*16 + lr)*136 + ki*32 + lh*8];
      #pragma unroll
      for (int nt = 0; nt < 2; nt++){
        const u16* wp = Wea + (size_t)(nb*128 + wv*32 + nt*16 + lr)*2048 + kc*128 + ki*32 + lh*8;
        bf16x8 bv = *(const bf16x8*)wp;
        #pragma unroll
        for (int mt = 0; mt < 4; mt++) acc[mt][nt] = MF(av[mt], bv, acc[mt][nt]);
      }
    }
  }
  #pragma unroll
  for (int nt = 0; nt < 2; nt++){
    int n = nb*128 + wv*32 + nt*16 + lr;
    float bias = bea[n];
    #pragma unroll
    for (int mt = 0; mt < 4; mt++){
      #pragma unroll
      for (int r = 0; r < 4; r++){
        int m = m0 + mt*16 + lh*4 + r;
        int bb = m / 196, pp = m - bb*196;
        att1T[((size_t)bb*512 + n)*208 + pp] = f2bf(acc[mt][nt][r] + bias);
      }
    }
  }
}

// ============ h,c init ============
__global__ __launch_bounds__(256) void k_init(const float* __restrict__ encm, const float* __restrict__ emb0,
    const float* __restrict__ Wh, const float* __restrict__ bh,
    const float* __restrict__ Wc, const float* __restrict__ bc,
    u16* __restrict__ h_bf, float* __restrict__ c){
  int mat = blockIdx.x >> 4, jb = blockIdx.x & 15;
  const float* W    = mat ? Wc : Wh;
  const float* bias = mat ? bc : bh;
  int j0 = jb*32;
  __shared__ float XT[256*36];
  int bq = threadIdx.x & 7, jq = threadIdx.x >> 3;
  float acc[4] = {0.f,0.f,0.f,0.f};
  for (int ch = 0; ch < 9; ch++){
    int k0 = ch*256;
    __syncthreads();
    {
      int m = threadIdx.x >> 3, kq8 = threadIdx.x & 7;
      #pragma unroll
      for (int i = 0; i < 8; i++){
        int kq = kq8 + i*8;
        int k = k0 + kq*4;
        float4 v;
        if (k < 2048) v = *(const float4*)&encm[m*ENCD + k];
        else          v = *(const float4*)&emb0[m*256 + (k - 2048)];
        XT[(4*kq+0)*36+m]=v.x; XT[(4*kq+1)*36+m]=v.y; XT[(4*kq+2)*36+m]=v.z; XT[(4*kq+3)*36+m]=v.w;
      }
    }
    __syncthreads();
    int j = j0 + jq;
    const float* wr = W + (size_t)j*XDIM + k0;
    #pragma unroll 2
    for (int k4 = 0; k4 < 64; k4++){
      float4 wv = *(const float4*)(wr + k4*4);
      float4 x0 = *(float4*)&XT[(k4*4+0)*36 + bq*4];
      float4 x1 = *(float4*)&XT[(k4*4+1)*36 + bq*4];
      float4 x2 = *(float4*)&XT[(k4*4+2)*36 + bq*4];
      float4 x3 = *(float4*)&XT[(k4*4+3)*36 + bq*4];
      acc[0] += x0.x*wv.x + x1.x*wv.y + x2.x*wv.z + x3.x*wv.w;
      acc[1] += x0.y*wv.x + x1.y*wv.y + x2.y*wv.z + x3.y*wv.w;
      acc[2] += x0.z*wv.x + x1.z*wv.y + x2.z*wv.z + x3.z*wv.w;
      acc[3] += x0.w*wv.x + x1.w*wv.y + x2.w*wv.z + x3.w*wv.w;
    }
  }
  #pragma unroll
  for (int bb = 0; bb < 4; bb++){
    float v = acc[bb] + bias[j0 + jq];
    int row = bq*4 + bb;
    if (mat == 0) h_bf[row*DECD + j0 + jq] = f2bf(v);
    else          c[row*DECD + j0 + jq] = v;
  }
}

// ============ kA: pA = h @ [Wdec|Wfb|Whh]^T ; preds/stop(t-1) ============
__global__ __launch_bounds__(256) void kA(const u16* __restrict__ h, const u16* __restrict__ WAP,
    float* __restrict__ pA, const float* __restrict__ bfc, const float* __restrict__ bstop,
    const int* __restrict__ len, float* __restrict__ out, int t){
  __shared__ u16 HL[32*520];
  int tid = threadIdx.x, wv = tid>>6, lane = tid&63, lr = lane&15, lh = lane>>4;
  for (int i = tid; i < 4096; i += 256){
    unsigned long long v = ((const unsigned long long*)h)[i];
    int row = i >> 7, col = (i & 127)*4;
    *(unsigned long long*)&HL[row*520 + col] = v;
  }
  __syncthreads();
  int j0 = blockIdx.x*64 + wv*16;
  f32x4 acc0 = {0,0,0,0}, acc1 = {0,0,0,0};
  #pragma unroll 4
  for (int ki = 0; ki < 16; ++ki){
    bf16x8 bv = *(const bf16x8*)&WAP[(size_t)(j0+lr)*512 + ki*32 + lh*8];
    bf16x8 a0 = *(const bf16x8*)&HL[lr*520 + ki*32 + lh*8];
    bf16x8 a1 = *(const bf16x8*)&HL[(16+lr)*520 + ki*32 + lh*8];
    acc0 = MF(a0, bv, acc0);
    acc1 = MF(a1, bv, acc1);
  }
  int j = j0 + lr;
  if (j < 4608){
    #pragma unroll
    for (int r = 0; r < 4; ++r){
      pA[(size_t)(lh*4+r)*4608 + j]    = acc0[r];
      pA[(size_t)(lh*4+r+16)*4608 + j] = acc1[r];
    }
  } else if (j < 4611 && t > 0){
    int jj = j - 4608, tm1 = t - 1;
    #pragma unroll
    for (int r = 0; r < 4; ++r){
      #pragma unroll
      for (int hb = 0; hb < 2; ++hb){
        int b0 = lh*4 + r + hb*16;
        float val = hb ? acc1[r] : acc0[r];
        bool mk = tm1 < len[b0];
        if (jj < 2) out[O_PRED + ((size_t)b0*64 + tm1)*2 + jj] = mk ? val + bfc[jj] : 0.f;
        else        out[O_STOP + (size_t)b0*64 + tm1] =
                      mk ? 1.f/(1.f + expf(-(val + bstop[0]))) : 0.f;
      }
    }
  }
}

// ============ kB1: score partials over a-chunks (coalesced along p) ============
__global__ __launch_bounds__(256) void kB1(const float* __restrict__ pA,
    const u16* __restrict__ att1T, const float* __restrict__ bdec,
    const float* __restrict__ wfull, float* __restrict__ scp,
    const int* __restrict__ len, int t){
  int b = blockIdx.x >> 3, ac = blockIdx.x & 7;
  if (t >= len[b]) return;
  __shared__ float a2s[64], wfs[64];
  int tid = threadIdx.x;
  if (tid < 64){
    int a = ac*64 + tid;
    a2s[tid] = pA[(size_t)b*4608 + a] + bdec[a];
    wfs[tid] = wfull[a];
  }
  __syncthreads();
  int p = tid;
  if (p < 196){
    const u16* col = att1T + ((size_t)b*512 + ac*64)*208 + p;
    float acc = 0.f;
    #pragma unroll 8
    for (int a = 0; a < 64; ++a)
      acc += fmaxf(bf2f(col[(size_t)a*208]) + a2s[a], 0.f) * wfs[a];
    scp[(size_t)(b*8 + ac)*200 + p] = acc;
  }
}

// ============ kB2: softmax + awe + gate -> xa ; alphas ============
__global__ __launch_bounds__(256) void kB2(const float* __restrict__ scp,
    const float* __restrict__ pA, const u16* __restrict__ encbf,
    const float* __restrict__ bfull, const float* __restrict__ bfb,
    u16* __restrict__ xa, const int* __restrict__ len, float* __restrict__ out, int t){
  int b = blockIdx.x >> 3, dc = blockIdx.x & 7;
  int tid = threadIdx.x, wv = tid>>6, lane = tid&63;
  if (t >= len[b]){
    if (dc == 0 && tid < 196) out[O_ALPHA + ((size_t)b*64 + t)*196 + tid] = 0.f;
    return;
  }
  __shared__ float ev[200], redf[4], bcx[2];
  float s = -1e30f;
  if (tid < 196){
    s = bfull[0];
    #pragma unroll
    for (int q = 0; q < 8; ++q) s += scp[(size_t)(b*8 + q)*200 + tid];
  }
  float m = s;
  #pragma unroll
  for (int o = 32; o; o >>= 1) m = fmaxf(m, __shfl_down(m, o));
  if (lane == 0) redf[wv] = m;
  __syncthreads();
  if (tid == 0) bcx[0] = fmaxf(fmaxf(redf[0],redf[1]), fmaxf(redf[2],redf[3]));
  __syncthreads();
  float e = (tid < 196) ? expf(s - bcx[0]) : 0.f;
  if (tid < 200) ev[tid] = (tid < 196) ? e : 0.f;
  float sm = e;
  #pragma unroll
  for (int o = 32; o; o >>= 1) sm += __shfl_down(sm, o);
  __syncthreads();
  if (lane == 0) redf[wv] = sm;
  __syncthreads();
  if (tid == 0) bcx[1] = redf[0]+redf[1]+redf[2]+redf[3];
  __syncthreads();
  float ssum = bcx[1];
  int d = dc*256 + tid;
  const u16* ep = encbf + (size_t)(b*196)*ENCD + d;
  float q[8];
  #pragma unroll
  for (int j = 0; j < 8; ++j) q[j] = 0.f;
  #pragma unroll 2
  for (int p = 0; p < 192; p += 8){
    #pragma unroll
    for (int j = 0; j < 8; ++j)
      q[j] += ev[p+j]*bf2f(ep[(size_t)(p+j)*ENCD]);
  }
  #pragma unroll
  for (int j = 0; j < 4; ++j)
    q[j] += ev[192+j]*bf2f(ep[(size_t)(192+j)*ENCD]);
  float awe = (((q[0]+q[1])+(q[2]+q[3])) + ((q[4]+q[5])+(q[6]+q[7]))) / ssum;
  float gp = pA[(size_t)b*4608 + 512 + d] + bfb[d];
  float gate = 1.f/(1.f + expf(-gp));
  xa[(size_t)b*2048 + d] = f2bf(gate * awe);
  if (dc == 0 && tid < 196) out[O_ALPHA + ((size_t)b*64 + t)*196 + tid] = ev[tid]/ssum;
}

// ============ kC: gates GEMM (8-wave K-split) + LSTM fused ============
__global__ __launch_bounds__(512) void kC(const u16* __restrict__ xa,
    const u16* __restrict__ hc, u16* __restrict__ hn, float* __restrict__ c,
    const u16* __restrict__ WIH2, const float* __restrict__ pA,
    const float* __restrict__ bcomb, const u16* __restrict__ gemb,
    const int* __restrict__ len, int t){
  int tid = threadIdx.x, wv = tid>>6, lane = tid&63, lr = lane&15, lh = lane>>4;
  int jp0 = blockIdx.x*16;
  __shared__ float red[8*512];
  f32x4 acc0 = {0,0,0,0}, acc1 = {0,0,0,0};
  #pragma unroll
  for (int ks = 0; ks < 8; ++ks){
    int k = wv*256 + ks*32;
    bf16x8 a0 = *(const bf16x8*)&xa[(size_t)lr*2048 + k + lh*8];
    bf16x8 a1 = *(const bf16x8*)&xa[(size_t)(16+lr)*2048 + k + lh*8];
    bf16x8 bv = *(const bf16x8*)&WIH2[(size_t)(jp0+lr)*2048 + k + lh*8];
    acc0 = MF(a0, bv, acc0);
    acc1 = MF(a1, bv, acc1);
  }
  #pragma unroll
  for (int r = 0; r < 4; ++r){
    red[wv*512 + ((lh*4+r) << 4) + lr]    = acc0[r];
    red[wv*512 + ((16+lh*4+r) << 4) + lr] = acc1[r];
  }
  __syncthreads();
  {
    int b = tid >> 4, jl = tid & 15, e = jl & 3;
    int jp = jp0 + jl, u = jp >> 2;
    float g = 0.f;
    #pragma unroll
    for (int w = 0; w < 8; ++w) g += red[w*512 + tid];
    g += bcomb[jp] + bf2f(gemb[((size_t)b*64 + t)*2048 + jp])
       + pA[(size_t)b*4608 + 2560 + e*512 + u];
    float sv = (e == 2) ? tanhf(g) : 1.f/(1.f + expf(-g));
    float vb = __shfl_xor(sv, 1), vc = __shfl_xor(sv, 2), vd = __shfl_xor(vb, 2);
    float i_s = (e==0)?sv:(e==1)?vb:(e==2)?vc:vd;
    float f_s = (e==1)?sv:(e==0)?vb:(e==3)?vc:vd;
    float g_t = (e==2)?sv:(e==3)?vb:(e==0)?vc:vd;
    float o_s = (e==3)?sv:(e==2)?vb:(e==1)?vc:vd;
    float cold = c[(size_t)b*512 + u];
    float hold = bf2f(hc[(size_t)b*512 + u]);
    bool mk = t < len[b];
    float cn = mk ? (f_s*cold + i_s*g_t) : cold;
    float hv = mk ? (o_s * tanhf(cn)) : hold;
    if (e == 0){
      c[(size_t)b*512 + u] = cn;
      hn[(size_t)b*512 + u] = f2bf(hv);
    }
  }
}

// ================= host launcher =================
extern "C" void kernel_launch(void* const* d_in, const int* in_sizes, int n_in,
                              void* d_out, int out_size, void* d_ws, size_t ws_size,
                              hipStream_t stream){
  (void)in_sizes; (void)n_in; (void)out_size; (void)ws_size;
  const float* enc_out   = (const float*)d_in[0];
  const float* imgs      = (const float*)d_in[1];
  const int*   seq       = (const int*)d_in[2];
  const float* seqoff    = (const float*)d_in[3];
  const int*   caplen    = (const int*)d_in[4];
  const float* W_pe      = (const float*)d_in[5];
  const float* b_pe      = (const float*)d_in[6];
  const float* W_enc_att = (const float*)d_in[7];
  const float* b_enc_att = (const float*)d_in[8];
  const float* W_dec_att = (const float*)d_in[9];
  const float* b_dec_att = (const float*)d_in[10];
  const float* w_full    = (const float*)d_in[11];
  const float* b_full    = (const float*)d_in[12];
  const float* W_init_h  = (const float*)d_in[13];
  const float* b_init_h  = (const float*)d_in[14];
  const float* W_init_c  = (const float*)d_in[15];
  const float* b_init_c  = (const float*)d_in[16];
  const float* W_fb      = (const float*)d_in[17];
  const float* b_fb      = (const float*)d_in[18];
  const float* W_ih      = (const float*)d_in[19];
  const float* b_ih      = (const float*)d_in[20];
  const float* W_hh      = (const float*)d_in[21];
  const float* b_hh      = (const float*)d_in[22];
  const float* W_fc      = (const float*)d_in[23];
  const float* b_fc      = (const float*)d_in[24];
  const float* W_stop    = (const float*)d_in[25];
  const float* b_stop    = (const float*)d_in[26];

  float* out = (float*)d_out;
  float* ws  = (float*)d_ws;
  int*   wsi = (int*)d_ws;
  u16*   us  = (u16*)d_ws;

  u16* H[2] = { us + US_H0, us + US_H1 };

  k_prep<<<1, 64, 0, stream>>>(caplen, wsi + WS_SORT, wsi + WS_LEN, out);
  k_seqoff<<<16, 256, 0, stream>>>(seqoff, wsi + WS_SORT, out);
  k_encbf<<<6272, 256, 0, stream>>>(enc_out, wsi + WS_SORT, us + US_ENC);
  k_encmean<<<256, 256, 0, stream>>>(us + US_ENC, ws + WS_ENCM);
  k_patch<<<2048, 256, 0, stream>>>(imgs, seq, wsi + WS_SORT, us + US_PATCH);
  k_embedv2<<<128, 256, 0, stream>>>(us + US_PATCH, W_pe, b_pe, us + US_EMBBF, ws + WS_EMB0);
  k_cvt2<<<7240, 256, 0, stream>>>(W_ih, W_hh, W_dec_att, W_fb, W_fc, W_stop, W_enc_att,
                                   b_ih, b_hh,
                                   us + US_WIH2, us + US_WIHE, us + US_WAP,
                                   us + US_WEA, ws + WS_BCOMB);
  k_att1v4<<<392, 256, 0, stream>>>(us + US_ENC, us + US_WEA, b_enc_att, us + US_ATT1T);
  k_gemb<<<256, 256, 0, stream>>>(us + US_EMBBF, us + US_WIHE, us + US_GEMB);
  k_init<<<32, 256, 0, stream>>>(ws + WS_ENCM, ws + WS_EMB0, W_init_h, b_init_h,
                                 W_init_c, b_init_c, H[0], ws + WS_C);

  for (int t = 0; t < Tn; ++t){
    kA<<<73, 256, 0, stream>>>(H[t & 1], us + US_WAP, ws + WS_PA, b_fc, b_stop,
                               wsi + WS_LEN, out, t);
    kB1<<<256, 256, 0, stream>>>(ws + WS_PA, us + US_ATT1T, b_dec_att, w_full,
                                 ws + WS_SCP, wsi + WS_LEN, t);
    kB2<<<256, 256, 0, stream>>>(ws + WS_SCP, ws + WS_PA, us + US_ENC, b_full, b_fb,
                                 us + US_XA, wsi + WS_LEN, out, t);
    kC<<<128, 512, 0, stream>>>(us + US_XA, H[t & 1], H[(t + 1) & 1], ws + WS_C,
                                us + US_WIH2, ws + WS_PA, ws + WS_BCOMB, us + US_GEMB,
                                wsi + WS_LEN, t);
  }
  kA<<<73, 256, 0, stream>>>(H[0], us + US_WAP, ws + WS_PA, b_fc, b_stop,
                             wsi + WS_LEN, out, 64);
}